// Round 5
// baseline (532.259 us; speedup 1.0000x reference)
//
#include <hip/hip_runtime.h>
#include <math.h>

#define NBINS 255
#define BIN_LO_F (-20.0f)
#define BIN_HI_F (20.0f)

typedef __attribute__((ext_vector_type(8))) short short8;
typedef __attribute__((ext_vector_type(16))) float f32x16;

__device__ __forceinline__ unsigned short f2bf(float f) {
    unsigned u = __builtin_bit_cast(unsigned, f);
    unsigned r = u + 0x7fffu + ((u >> 16) & 1u);
    return (unsigned short)(r >> 16);
}

// packed RNE f32x2 -> bf16x2 (T12 recipe; no builtin on gfx950)
__device__ __forceinline__ unsigned pkbf(float lo, float hi) {
    unsigned d;
    asm("v_cvt_pk_bf16_f32 %0, %1, %2" : "=v"(d) : "v"(lo), "v"(hi));
    return d;
}

__device__ __forceinline__ short8 mk8(unsigned a, unsigned b, unsigned c, unsigned d) {
    union { unsigned u[4]; short8 s; } t;
    t.u[0] = a; t.u[1] = b; t.u[2] = c; t.u[3] = d;
    return t.s;
}

__device__ __forceinline__ double wave_reduce_sum_d(double v) {
    #pragma unroll
    for (int m = 32; m >= 1; m >>= 1) v += __shfl_xor(v, m, 64);
    return v;
}

// Pack W (D,255) fp32 -> bf16 Wpack2, per-wave-slice chunk layout:
// entry t -> g = t/(64*kc), c = (t/64)%kc, e = t%64  (kc = D/16)
// content: col = g*32 + (e&31), k = c*16 + (e>>5)*8 + j, j=0..7; col 255 zero pad.
// In the GEMM, wave g's chunk c B-frag is ONE contiguous 1KB block: lane reads 16B at
// Wpack2 + g*(kc*1024) + c*1024 + (lhi*32+l31)*16.
__global__ __launch_bounds__(256) void pack_w2(
    const float* __restrict__ W, char* __restrict__ Wpack2, int kc)
{
    int t = blockIdx.x * 256 + threadIdx.x;
    int e = t & 63;
    int rem = t >> 6;
    int c = rem % kc;
    int g = rem / kc;
    int col = g * 32 + (e & 31);
    int k0 = c * 16 + (e >> 5) * 8;
    short8 s;
    #pragma unroll
    for (int j = 0; j < 8; ++j)
        s[j] = (col < NBINS) ? (short)f2bf(W[(size_t)(k0 + j) * NBINS + col]) : (short)0;
    *(short8*)(Wpack2 + (size_t)t * 16) = s;
}

// Barrier-free MFMA GEMM v5. Block = 64 rows x 256 cols, 512 thr = 8 waves = 8 col-groups
// of 32 cols, full K per wave (no K-split -> no combine). B: 1 contiguous dwordx4 per
// chunk per lane from L2-resident Wpack2 (read once per block). A: per-lane global fp32
// (L1-shared across the 8 waves), cvt_pk -> bf16. 4-set static register pipeline
// (effective prefetch depth ~3 chunks). acc: 2 x f32x16 (rows 0-31 / 32-63).
__global__ __launch_bounds__(512, 2) void gemm_mfma_v5(
    const float* __restrict__ latents, const float* __restrict__ boot,
    const char* __restrict__ Wpack2, const float* __restrict__ bvec,
    float* __restrict__ logits, int NR, int R, int D)
{
    const int tid  = threadIdx.x;
    const int wave = tid >> 6, lane = tid & 63;
    const int l31  = lane & 31, lhi = lane >> 5;
    const int row0 = blockIdx.x * 64;
    const int kc   = D >> 4;           // chunks of K=16

    // A bases: lane covers row row0+l31 (block 0) and row0+32+l31 (block 1), k-half lhi
    int ra = row0 + l31, rb = row0 + 32 + l31;
    const float* aptrA = ((ra < NR) ? latents + (size_t)ra * D
                                    : boot + (size_t)(ra - NR) * D) + lhi * 8;
    const float* aptrB = ((rb < NR) ? latents + (size_t)rb * D
                                    : boot + (size_t)(rb - NR) * D) + lhi * 8;
    const char* bptr = Wpack2 + (size_t)wave * ((size_t)kc * 1024)
                              + (size_t)(lhi * 32 + l31) * 16;

    f32x16 acc0, acc1;
    #pragma unroll
    for (int r = 0; r < 16; ++r) { acc0[r] = 0.f; acc1[r] = 0.f; }

    float4 A0_0, A0_1, A0_2, A0_3; short8 B0;
    float4 A1_0, A1_1, A1_2, A1_3; short8 B1;
    float4 A2_0, A2_1, A2_2, A2_3; short8 B2;
    float4 A3_0, A3_1, A3_2, A3_3; short8 B3;

#define PREFETCH(S, CC) do {                                         \
        const float* apA_ = aptrA + (size_t)(CC) * 16;               \
        A##S##_0 = *(const float4*)(apA_);                           \
        A##S##_1 = *(const float4*)(apA_ + 4);                       \
        const float* apB_ = aptrB + (size_t)(CC) * 16;               \
        A##S##_2 = *(const float4*)(apB_);                           \
        A##S##_3 = *(const float4*)(apB_ + 4);                       \
        B##S = *(const short8*)(bptr + (size_t)(CC) * 1024);         \
    } while (0)

#define COMPUTE(S) do {                                              \
        short8 af0_ = mk8(pkbf(A##S##_0.x, A##S##_0.y),              \
                          pkbf(A##S##_0.z, A##S##_0.w),              \
                          pkbf(A##S##_1.x, A##S##_1.y),              \
                          pkbf(A##S##_1.z, A##S##_1.w));             \
        short8 af1_ = mk8(pkbf(A##S##_2.x, A##S##_2.y),              \
                          pkbf(A##S##_2.z, A##S##_2.w),              \
                          pkbf(A##S##_3.x, A##S##_3.y),              \
                          pkbf(A##S##_3.z, A##S##_3.w));             \
        acc0 = __builtin_amdgcn_mfma_f32_32x32x16_bf16(af0_, B##S, acc0, 0, 0, 0); \
        acc1 = __builtin_amdgcn_mfma_f32_32x32x16_bf16(af1_, B##S, acc1, 0, 0, 0); \
    } while (0)

    // prologue: prime 4 chunks
    PREFETCH(0, 0); PREFETCH(1, 1); PREFETCH(2, 2); PREFETCH(3, 3);

    int c = 0;
    for (; c < kc - 4; c += 4) {
        COMPUTE(0); PREFETCH(0, c + 4);
        COMPUTE(1); PREFETCH(1, c + 5);
        COMPUTE(2); PREFETCH(2, c + 6);
        COMPUTE(3); PREFETCH(3, c + 7);
    }
    // tail: last 4 chunks, no prefetch
    COMPUTE(0); COMPUTE(1); COMPUTE(2); COMPUTE(3);

#undef PREFETCH
#undef COMPUTE

    // epilogue: wave's private 64x32 tile. C layout: col=lane&31, row=(r&3)+8*(r>>2)+4*lhi
    int col = wave * 32 + l31;
    if (col < NBINS) {
        float bias = bvec[col];
        #pragma unroll
        for (int r = 0; r < 16; ++r) {
            int row = row0 + (r & 3) + 8 * (r >> 2) + 4 * lhi;
            logits[(size_t)row * NBINS + col] = acc0[r] + bias;
        }
        #pragma unroll
        for (int r = 0; r < 16; ++r) {
            int row = row0 + 32 + (r & 3) + 8 * (r >> 2) + 4 * lhi;
            logits[(size_t)row * NBINS + col] = acc1[r] + bias;
        }
    }
}

// per-row softmax stats: value = softmax(l)@centers, logZ
__global__ __launch_bounds__(256) void softmax_stats(
    const float* __restrict__ logits, float* __restrict__ values,
    float* __restrict__ logZ, int R)
{
    int row  = blockIdx.x * 4 + (threadIdx.x >> 6);
    int lane = threadIdx.x & 63;
    if (row >= R) return;
    const float* lp = logits + (size_t)row * NBINS;
    const float step = (float)(40.0 / 254.0);

    float l[4];
    float m = -INFINITY;
    #pragma unroll
    for (int u = 0; u < 4; ++u) {
        int idx = lane + 64 * u;
        l[u] = (idx < NBINS) ? lp[idx] : -INFINITY;
        m = fmaxf(m, l[u]);
    }
    #pragma unroll
    for (int sh = 32; sh >= 1; sh >>= 1) m = fmaxf(m, __shfl_xor(m, sh, 64));

    float s = 0.f, sc = 0.f;
    #pragma unroll
    for (int u = 0; u < 4; ++u) {
        int idx = lane + 64 * u;
        if (idx < NBINS) {
            float e = __expf(l[u] - m);
            s  += e;
            sc += e * (BIN_LO_F + step * (float)idx);
        }
    }
    #pragma unroll
    for (int sh = 32; sh >= 1; sh >>= 1) {
        s  += __shfl_xor(s, sh, 64);
        sc += __shfl_xor(sc, sh, 64);
    }
    if (lane == 0) {
        values[row] = sc / s;
        logZ[row]   = m + __logf(s);
    }
}

__global__ void lambda_returns_k(
    const float* __restrict__ rewards, const float* __restrict__ dones,
    const float* __restrict__ values, float* __restrict__ returns,
    int B, int H, int NR)
{
    int b = blockIdx.x * blockDim.x + threadIdx.x;
    if (b >= B) return;
    const float gamma = 0.997f;
    const float lam   = 0.95f;
    const float oml   = (float)(1.0 - 0.95);
    float bootv = values[NR + b];
    float g = bootv;
    for (int h = H - 1; h >= 0; --h) {
        float nv   = (h == H - 1) ? bootv : values[b * H + h + 1];
        float mask = 1.0f - dones[b * H + h];
        g = rewards[b * H + h] + gamma * mask * (oml * nv + lam * g);
        returns[b * H + h] = g;
    }
}

__global__ __launch_bounds__(256) void loss_moments(
    const float* __restrict__ logits, const float* __restrict__ logZ,
    const float* __restrict__ values, const float* __restrict__ returns,
    double* __restrict__ accum, int NR)
{
    int row = blockIdx.x * blockDim.x + threadIdx.x;
    double lsum = 0, vsum = 0, v2 = 0, rsum = 0, r2 = 0;
    if (row < NR) {
        float v   = values[row];
        float ret = returns[row];
        float cl  = fminf(fmaxf(ret, BIN_LO_F), BIN_HI_F);
        const float step = (float)(40.0 / 254.0);
        float pos = (cl - BIN_LO_F) / step;
        int low = (int)floorf(pos);
        low = min(max(low, 0), NBINS - 2);
        float frac = pos - (float)low;
        const float* lp = logits + (size_t)row * NBINS;
        float llo = lp[low], lhi = lp[low + 1];
        float loss = logZ[row] - (1.f - frac) * llo - frac * lhi;
        lsum = (double)loss;
        vsum = (double)v;   v2 = (double)v * (double)v;
        rsum = (double)ret; r2 = (double)ret * (double)ret;
    }
    lsum = wave_reduce_sum_d(lsum);
    vsum = wave_reduce_sum_d(vsum);
    v2   = wave_reduce_sum_d(v2);
    rsum = wave_reduce_sum_d(rsum);
    r2   = wave_reduce_sum_d(r2);
    if ((threadIdx.x & 63) == 0) {
        atomicAdd(&accum[0], lsum);
        atomicAdd(&accum[1], vsum);
        atomicAdd(&accum[2], v2);
        atomicAdd(&accum[3], rsum);
        atomicAdd(&accum[4], r2);
    }
}

__global__ void finalize_k(const double* __restrict__ accum,
                           float* __restrict__ out, int NR)
{
    if (threadIdx.x == 0 && blockIdx.x == 0) {
        double n  = (double)NR;
        double vl = accum[0] / n;
        double mv = accum[1] / n;
        double vv = (accum[2] - n * mv * mv) / (n - 1.0);
        double mr = accum[3] / n;
        double vr = (accum[4] - n * mr * mr) / (n - 1.0);
        out[0] = (float)(0.5 * vl);
        out[1] = (float)vl;
        out[2] = (float)mv;
        out[3] = (float)mr;
        out[4] = (float)sqrt(vv > 0.0 ? vv : 0.0);
        out[5] = (float)sqrt(vr > 0.0 ? vr : 0.0);
    }
}

extern "C" void kernel_launch(void* const* d_in, const int* in_sizes, int n_in,
                              void* d_out, int out_size, void* d_ws, size_t ws_size,
                              hipStream_t stream) {
    const float* latents = (const float*)d_in[0];
    const float* rewards = (const float*)d_in[1];
    const float* dones   = (const float*)d_in[2];
    const float* boot    = (const float*)d_in[3];
    const float* W       = (const float*)d_in[4];
    const float* bvec    = (const float*)d_in[5];
    float* out = (float*)d_out;

    const int BH = in_sizes[1];          // B*H = 16384
    const int D  = in_sizes[0] / BH;     // 4096
    const int B  = in_sizes[3] / D;      // 1024
    const int H  = BH / B;               // 16
    const int NR = BH;
    const int R  = NR + B;               // 17408

    char* ws = (char*)d_ws;
    size_t off = 0;
    float* logits = (float*)(ws + off); off += (size_t)R * NBINS * sizeof(float);
    off = (off + 255) & ~(size_t)255;
    float* values = (float*)(ws + off); off += (size_t)R * sizeof(float);
    float* logZ   = (float*)(ws + off); off += (size_t)R * sizeof(float);
    float* rets   = (float*)(ws + off); off += (size_t)NR * sizeof(float);
    off = (off + 255) & ~(size_t)255;
    double* accum = (double*)(ws + off); off += 64;
    off = (off + 255) & ~(size_t)255;
    char* Wpack2  = ws + off; off += (size_t)(D / 16) * 8 * 1024;   // 2 MB

    hipMemsetAsync(accum, 0, 64, stream);

    const int kc = D / 16;
    const int packThreads = 8 * kc * 64;    // one 16B entry per thread
    pack_w2<<<packThreads / 256, 256, 0, stream>>>(W, Wpack2, kc);
    gemm_mfma_v5<<<R / 64, 512, 0, stream>>>(latents, boot, Wpack2, bvec, logits, NR, R, D);
    softmax_stats<<<(R + 3) / 4, 256, 0, stream>>>(logits, values, logZ, R);
    lambda_returns_k<<<(B + 255) / 256, 256, 0, stream>>>(rewards, dones, values, rets, B, H, NR);
    loss_moments<<<(NR + 255) / 256, 256, 0, stream>>>(logits, logZ, values, rets, accum, NR);
    finalize_k<<<1, 64, 0, stream>>>(accum, out, NR);
}

// Round 6
// 273.166 us; speedup vs baseline: 1.9485x; 1.9485x over previous
//
#include <hip/hip_runtime.h>
#include <math.h>

#define NBINS 255
#define BIN_LO_F (-20.0f)
#define BIN_HI_F (20.0f)

typedef __attribute__((ext_vector_type(8))) short short8;
typedef __attribute__((ext_vector_type(16))) float f32x16;

__device__ __forceinline__ unsigned short f2bf(float f) {
    unsigned u = __builtin_bit_cast(unsigned, f);
    unsigned r = u + 0x7fffu + ((u >> 16) & 1u);
    return (unsigned short)(r >> 16);
}

// packed RNE f32x2 -> bf16x2
__device__ __forceinline__ unsigned pkbf(float lo, float hi) {
    unsigned d;
    asm("v_cvt_pk_bf16_f32 %0, %1, %2" : "=v"(d) : "v"(lo), "v"(hi));
    return d;
}

__device__ __forceinline__ short8 mk8(unsigned a, unsigned b, unsigned c, unsigned d) {
    union { unsigned u[4]; short8 s; } t;
    t.u[0] = a; t.u[1] = b; t.u[2] = c; t.u[3] = d;
    return t.s;
}

__device__ __forceinline__ void glds16(const void* g, void* l) {
    __builtin_amdgcn_global_load_lds(
        (const __attribute__((address_space(1))) unsigned int*)g,
        (__attribute__((address_space(3))) unsigned int*)l, 16, 0, 0);
}

__device__ __forceinline__ double wave_reduce_sum_d(double v) {
    #pragma unroll
    for (int m = 32; m >= 1; m >>= 1) v += __shfl_xor(v, m, 64);
    return v;
}

// Pack W (D,255) fp32 -> bf16 WpackB, LDS-image layout per (ktile, nhalf):
// 16B unit u: kt=u>>11, nh=(u>>10)&1, v=u&1023: ks=v>>8, cb=(v>>6)&3, kh=(v>>5)&1, col=v&31
// content: column C = nh*128+cb*32+col (255 -> zero pad), k = kt*64+ks*16+kh*8+e.
// GEMM ds_read of one B-frag is then a LINEAR 16B/lane read (zero bank conflicts).
__global__ __launch_bounds__(256) void pack_w3(
    const float* __restrict__ W, char* __restrict__ WpackB)
{
    int u = blockIdx.x * 256 + threadIdx.x;
    int kt = u >> 11;
    int r  = u & 2047;
    int nh = r >> 10;
    int v  = r & 1023;
    int ks = v >> 8;
    int cb = (v >> 6) & 3;
    int kh = (v >> 5) & 1;
    int col = v & 31;
    int C  = nh * 128 + cb * 32 + col;
    int k0 = kt * 64 + ks * 16 + kh * 8;
    short8 s;
    #pragma unroll
    for (int e = 0; e < 8; ++e)
        s[e] = (C < NBINS) ? (short)f2bf(W[(size_t)(k0 + e) * NBINS + C]) : (short)0;
    *(short8*)(WpackB + (size_t)u * 16) = s;
}

// T3/T4 2-phase counted-vmcnt MFMA GEMM. BM=64 x BN=128, grid 544, 256 thr = 4 waves
// (2M x 2N), wave tile 32x64, acc 2 x f32x16. B: 4 global_load_lds/wave/K-tile into
// linear LDS image (dbuf 32KB); A: per-lane global fp32 -> cvt_pk bf16 (MFMA-native
// frag), static double-buffered regs. Per tile: bar1; STAGE(t+1)+LOADA(t+1);
// vmcnt(12); bar2; COMPUTE(t). vmcnt never 0 in the main loop.
__global__ __launch_bounds__(256, 3) void gemm_mfma_v6(
    const float* __restrict__ latents, const float* __restrict__ boot,
    const char* __restrict__ WpackB, const float* __restrict__ bvec,
    float* __restrict__ logits, int NR, int R, int D, int nwg8)
{
    __shared__ __align__(16) char ldsB[2][16384];
    const int tid  = threadIdx.x;
    const int wave = tid >> 6, lane = tid & 63;
    const int l31  = lane & 31, lhi = lane >> 5;
    const int mw   = wave & 1, nw = wave >> 1;
    const int NT   = D >> 6;

    // XCD-aware swizzle (544 % 8 == 0 -> bijective): consecutive work on one XCD
    int bid  = blockIdx.x;
    int work = (bid & 7) * nwg8 + (bid >> 3);
    int mt   = work >> 1, nh = work & 1;
    const int row0 = mt * 64;

    int rowg = row0 + mw * 32 + l31;
    const float* aptr = ((rowg < NR) ? latents + (size_t)rowg * D
                                     : boot + (size_t)(rowg - NR) * D) + lhi * 8;
    const char* bsrc = WpackB + (size_t)nh * 16384;   // tile t at + t*32768

    f32x16 acc0, acc1;
    #pragma unroll
    for (int r = 0; r < 16; ++r) { acc0[r] = 0.f; acc1[r] = 0.f; }

    float4 Aa[8], Ab[8];
    const int stoff = wave * 4096 + lane * 16;   // this wave's 4KB staging slice

#define STAGE(T, BUF) do {                                           \
        const char* s_ = bsrc + (size_t)(T) * 32768 + stoff;         \
        char* d_ = &ldsB[BUF][0] + stoff;                            \
        glds16(s_,        d_);                                       \
        glds16(s_ + 1024, d_ + 1024);                                \
        glds16(s_ + 2048, d_ + 2048);                                \
        glds16(s_ + 3072, d_ + 3072);                                \
    } while (0)

#define LOADA(SET, T) do {                                           \
        const float* a_ = aptr + (size_t)(T) * 64;                   \
        SET[0] = *(const float4*)(a_);      SET[1] = *(const float4*)(a_ + 4);  \
        SET[2] = *(const float4*)(a_ + 16); SET[3] = *(const float4*)(a_ + 20); \
        SET[4] = *(const float4*)(a_ + 32); SET[5] = *(const float4*)(a_ + 36); \
        SET[6] = *(const float4*)(a_ + 48); SET[7] = *(const float4*)(a_ + 52); \
    } while (0)

#define COMPUTE(BUF, SET) do {                                       \
        const char* base_ = &ldsB[BUF][0] + nw * 2048 + lhi * 512 + l31 * 16; \
        _Pragma("unroll")                                            \
        for (int ks = 0; ks < 4; ++ks) {                             \
            short8 b0_ = *(const short8*)(base_ + ks * 4096);        \
            short8 b1_ = *(const short8*)(base_ + ks * 4096 + 1024); \
            short8 a_  = mk8(pkbf(SET[2*ks].x, SET[2*ks].y),         \
                             pkbf(SET[2*ks].z, SET[2*ks].w),         \
                             pkbf(SET[2*ks+1].x, SET[2*ks+1].y),     \
                             pkbf(SET[2*ks+1].z, SET[2*ks+1].w));    \
            acc0 = __builtin_amdgcn_mfma_f32_32x32x16_bf16(a_, b0_, acc0, 0, 0, 0); \
            acc1 = __builtin_amdgcn_mfma_f32_32x32x16_bf16(a_, b1_, acc1, 0, 0, 0); \
        }                                                            \
    } while (0)

#define BAR()   __builtin_amdgcn_s_barrier()
#define SCHED() __builtin_amdgcn_sched_barrier(0)
#define WAITV12() asm volatile("s_waitcnt vmcnt(12)" ::: "memory")
#define WAITV0()  asm volatile("s_waitcnt vmcnt(0)"  ::: "memory")

    // prologue: stage tile 0 into L0, A(0) into Aa
    STAGE(0, 0); LOADA(Aa, 0);

    for (int t = 0; t + 3 < NT; t += 2) {
        BAR(); SCHED();                      // buf1 free (readers of t-1 done)
        STAGE(t + 1, 1); LOADA(Ab, t + 1);
        SCHED(); WAITV12(); BAR(); SCHED();  // S(t) landed everywhere
        COMPUTE(0, Aa);                      // tile t
        BAR(); SCHED();                      // buf0 free
        STAGE(t + 2, 0); LOADA(Aa, t + 2);
        SCHED(); WAITV12(); BAR(); SCHED();  // S(t+1) landed
        COMPUTE(1, Ab);                      // tile t+1
    }
    // tail: tiles NT-2 (L0/Aa) and NT-1
    BAR(); SCHED();
    STAGE(NT - 1, 1); LOADA(Ab, NT - 1);
    SCHED(); WAITV12(); BAR(); SCHED();
    COMPUTE(0, Aa);                          // tile NT-2
    BAR(); SCHED();
    WAITV0(); BAR(); SCHED();
    COMPUTE(1, Ab);                          // tile NT-1

#undef STAGE
#undef LOADA
#undef COMPUTE
#undef BAR
#undef SCHED
#undef WAITV12
#undef WAITV0

    // epilogue: wave stores its 32x64 tile. C layout: col=lane&31, row=(r&3)+8*(r>>2)+4*lhi
    #pragma unroll
    for (int i = 0; i < 2; ++i) {
        int col = nh * 128 + nw * 64 + i * 32 + l31;
        if (col < NBINS) {
            float bias = bvec[col];
            const f32x16& a = i ? acc1 : acc0;
            #pragma unroll
            for (int r = 0; r < 16; ++r) {
                int row = row0 + mw * 32 + (r & 3) + 8 * (r >> 2) + 4 * lhi;
                logits[(size_t)row * NBINS + col] = a[r] + bias;
            }
        }
    }
}

// per-row softmax stats: value = softmax(l)@centers, logZ
__global__ __launch_bounds__(256) void softmax_stats(
    const float* __restrict__ logits, float* __restrict__ values,
    float* __restrict__ logZ, int R)
{
    int row  = blockIdx.x * 4 + (threadIdx.x >> 6);
    int lane = threadIdx.x & 63;
    if (row >= R) return;
    const float* lp = logits + (size_t)row * NBINS;
    const float step = (float)(40.0 / 254.0);

    float l[4];
    float m = -INFINITY;
    #pragma unroll
    for (int u = 0; u < 4; ++u) {
        int idx = lane + 64 * u;
        l[u] = (idx < NBINS) ? lp[idx] : -INFINITY;
        m = fmaxf(m, l[u]);
    }
    #pragma unroll
    for (int sh = 32; sh >= 1; sh >>= 1) m = fmaxf(m, __shfl_xor(m, sh, 64));

    float s = 0.f, sc = 0.f;
    #pragma unroll
    for (int u = 0; u < 4; ++u) {
        int idx = lane + 64 * u;
        if (idx < NBINS) {
            float e = __expf(l[u] - m);
            s  += e;
            sc += e * (BIN_LO_F + step * (float)idx);
        }
    }
    #pragma unroll
    for (int sh = 32; sh >= 1; sh >>= 1) {
        s  += __shfl_xor(s, sh, 64);
        sc += __shfl_xor(sc, sh, 64);
    }
    if (lane == 0) {
        values[row] = sc / s;
        logZ[row]   = m + __logf(s);
    }
}

__global__ void lambda_returns_k(
    const float* __restrict__ rewards, const float* __restrict__ dones,
    const float* __restrict__ values, float* __restrict__ returns,
    int B, int H, int NR)
{
    int b = blockIdx.x * blockDim.x + threadIdx.x;
    if (b >= B) return;
    const float gamma = 0.997f;
    const float lam   = 0.95f;
    const float oml   = (float)(1.0 - 0.95);
    float bootv = values[NR + b];
    float g = bootv;
    for (int h = H - 1; h >= 0; --h) {
        float nv   = (h == H - 1) ? bootv : values[b * H + h + 1];
        float mask = 1.0f - dones[b * H + h];
        g = rewards[b * H + h] + gamma * mask * (oml * nv + lam * g);
        returns[b * H + h] = g;
    }
}

__global__ __launch_bounds__(256) void loss_moments(
    const float* __restrict__ logits, const float* __restrict__ logZ,
    const float* __restrict__ values, const float* __restrict__ returns,
    double* __restrict__ accum, int NR)
{
    int row = blockIdx.x * blockDim.x + threadIdx.x;
    double lsum = 0, vsum = 0, v2 = 0, rsum = 0, r2 = 0;
    if (row < NR) {
        float v   = values[row];
        float ret = returns[row];
        float cl  = fminf(fmaxf(ret, BIN_LO_F), BIN_HI_F);
        const float step = (float)(40.0 / 254.0);
        float pos = (cl - BIN_LO_F) / step;
        int low = (int)floorf(pos);
        low = min(max(low, 0), NBINS - 2);
        float frac = pos - (float)low;
        const float* lp = logits + (size_t)row * NBINS;
        float llo = lp[low], lhi = lp[low + 1];
        float loss = logZ[row] - (1.f - frac) * llo - frac * lhi;
        lsum = (double)loss;
        vsum = (double)v;   v2 = (double)v * (double)v;
        rsum = (double)ret; r2 = (double)ret * (double)ret;
    }
    lsum = wave_reduce_sum_d(lsum);
    vsum = wave_reduce_sum_d(vsum);
    v2   = wave_reduce_sum_d(v2);
    rsum = wave_reduce_sum_d(rsum);
    r2   = wave_reduce_sum_d(r2);
    if ((threadIdx.x & 63) == 0) {
        atomicAdd(&accum[0], lsum);
        atomicAdd(&accum[1], vsum);
        atomicAdd(&accum[2], v2);
        atomicAdd(&accum[3], rsum);
        atomicAdd(&accum[4], r2);
    }
}

__global__ void finalize_k(const double* __restrict__ accum,
                           float* __restrict__ out, int NR)
{
    if (threadIdx.x == 0 && blockIdx.x == 0) {
        double n  = (double)NR;
        double vl = accum[0] / n;
        double mv = accum[1] / n;
        double vv = (accum[2] - n * mv * mv) / (n - 1.0);
        double mr = accum[3] / n;
        double vr = (accum[4] - n * mr * mr) / (n - 1.0);
        out[0] = (float)(0.5 * vl);
        out[1] = (float)vl;
        out[2] = (float)mv;
        out[3] = (float)mr;
        out[4] = (float)sqrt(vv > 0.0 ? vv : 0.0);
        out[5] = (float)sqrt(vr > 0.0 ? vr : 0.0);
    }
}

extern "C" void kernel_launch(void* const* d_in, const int* in_sizes, int n_in,
                              void* d_out, int out_size, void* d_ws, size_t ws_size,
                              hipStream_t stream) {
    const float* latents = (const float*)d_in[0];
    const float* rewards = (const float*)d_in[1];
    const float* dones   = (const float*)d_in[2];
    const float* boot    = (const float*)d_in[3];
    const float* W       = (const float*)d_in[4];
    const float* bvec    = (const float*)d_in[5];
    float* out = (float*)d_out;

    const int BH = in_sizes[1];          // B*H = 16384
    const int D  = in_sizes[0] / BH;     // 4096
    const int B  = in_sizes[3] / D;      // 1024
    const int H  = BH / B;               // 16
    const int NR = BH;
    const int R  = NR + B;               // 17408

    char* ws = (char*)d_ws;
    size_t off = 0;
    float* logits = (float*)(ws + off); off += (size_t)R * NBINS * sizeof(float);
    off = (off + 255) & ~(size_t)255;
    float* values = (float*)(ws + off); off += (size_t)R * sizeof(float);
    float* logZ   = (float*)(ws + off); off += (size_t)R * sizeof(float);
    float* rets   = (float*)(ws + off); off += (size_t)NR * sizeof(float);
    off = (off + 255) & ~(size_t)255;
    double* accum = (double*)(ws + off); off += 64;
    off = (off + 255) & ~(size_t)255;
    char* WpackB  = ws + off; off += (size_t)(D / 64) * 32768;   // 2 MB

    hipMemsetAsync(accum, 0, 64, stream);

    const int NT = D / 64;
    const int packUnits = NT * 2048;                 // 16B units
    pack_w3<<<packUnits / 256, 256, 0, stream>>>(W, WpackB);

    const int nwg = 2 * (R / 64);                    // 544
    gemm_mfma_v6<<<nwg, 256, 0, stream>>>(latents, boot, WpackB, bvec, logits,
                                          NR, R, D, nwg / 8);
    softmax_stats<<<(R + 3) / 4, 256, 0, stream>>>(logits, values, logZ, R);
    lambda_returns_k<<<(B + 255) / 256, 256, 0, stream>>>(rewards, dones, values, rets, B, H, NR);
    loss_moments<<<(NR + 255) / 256, 256, 0, stream>>>(logits, logZ, values, rets, accum, NR);
    finalize_k<<<1, 64, 0, stream>>>(accum, out, NR);
}

// Round 7
// 269.332 us; speedup vs baseline: 1.9762x; 1.0142x over previous
//
#include <hip/hip_runtime.h>
#include <math.h>

#define NBINS 255
#define BIN_LO_F (-20.0f)
#define BIN_HI_F (20.0f)

typedef __attribute__((ext_vector_type(8))) short short8;
typedef __attribute__((ext_vector_type(16))) float f32x16;

__device__ __forceinline__ unsigned short f2bf(float f) {
    unsigned u = __builtin_bit_cast(unsigned, f);
    unsigned r = u + 0x7fffu + ((u >> 16) & 1u);
    return (unsigned short)(r >> 16);
}

// packed RNE f32x2 -> bf16x2
__device__ __forceinline__ unsigned pkbf(float lo, float hi) {
    unsigned d;
    asm("v_cvt_pk_bf16_f32 %0, %1, %2" : "=v"(d) : "v"(lo), "v"(hi));
    return d;
}

__device__ __forceinline__ short8 mk8(unsigned a, unsigned b, unsigned c, unsigned d) {
    union { unsigned u[4]; short8 s; } t;
    t.u[0] = a; t.u[1] = b; t.u[2] = c; t.u[3] = d;
    return t.s;
}

__device__ __forceinline__ void glds16(const void* g, void* l) {
    __builtin_amdgcn_global_load_lds(
        (const __attribute__((address_space(1))) unsigned int*)g,
        (__attribute__((address_space(3))) unsigned int*)l, 16, 0, 0);
}

__device__ __forceinline__ double wave_reduce_sum_d(double v) {
    #pragma unroll
    for (int m = 32; m >= 1; m >>= 1) v += __shfl_xor(v, m, 64);
    return v;
}

// Pack W (D,255) fp32 -> bf16 WpackB, LDS-image layout per (ktile, nhalf):
// 16B unit u: kt=u>>11, nh=(u>>10)&1, v=u&1023: ks=v>>8, cb=(v>>6)&3, kh=(v>>5)&1, col=v&31
// content: column C = nh*128+cb*32+col (255 -> zero pad), k = kt*64+ks*16+kh*8+e.
__global__ __launch_bounds__(256) void pack_w3(
    const float* __restrict__ W, char* __restrict__ WpackB)
{
    int u = blockIdx.x * 256 + threadIdx.x;
    int kt = u >> 11;
    int r  = u & 2047;
    int nh = r >> 10;
    int v  = r & 1023;
    int ks = v >> 8;
    int cb = (v >> 6) & 3;
    int kh = (v >> 5) & 1;
    int col = v & 31;
    int C  = nh * 128 + cb * 32 + col;
    int k0 = kt * 64 + ks * 16 + kh * 8;
    short8 s;
    #pragma unroll
    for (int e = 0; e < 8; ++e)
        s[e] = (C < NBINS) ? (short)f2bf(W[(size_t)(k0 + e) * NBINS + C]) : (short)0;
    *(short8*)(WpackB + (size_t)u * 16) = s;
}

// T3/T4 counted-vmcnt MFMA GEMM, DEPTH-3 pipeline (4 LDS buffers).
// BM=64 x BN=128, 256 thr = 4 waves (2M x 2N), wave tile 32x64, acc 2 x f32x16.
// Per phase: BAR(buf free); issue batch for tile t+3 (4 glds + 8 A-loads = 12 VMEM);
// vmcnt(36) = 3 batches in flight; BAR(data ready); COMPUTE(t). Depth-3 -> the batch
// consumed each phase was issued ~3 phases earlier, covering ~900cyc HBM/L3 latency.
__global__ __launch_bounds__(256, 2) void gemm_mfma_v7(
    const float* __restrict__ latents, const float* __restrict__ boot,
    const char* __restrict__ WpackB, const float* __restrict__ bvec,
    float* __restrict__ logits, int NR, int R, int D, int nwg8)
{
    __shared__ __align__(16) char ldsB[4][16384];
    const int tid  = threadIdx.x;
    const int wave = tid >> 6, lane = tid & 63;
    const int l31  = lane & 31, lhi = lane >> 5;
    const int mw   = wave & 1, nw = wave >> 1;
    const int NT   = D >> 6;   // 64 (assumed % 4 == 0)

    // XCD-aware swizzle (544 % 8 == 0 -> bijective); (mt,nh=0/1) land adjacent on one XCD
    int bid  = blockIdx.x;
    int work = (bid & 7) * nwg8 + (bid >> 3);
    int mt   = work >> 1, nh = work & 1;
    const int row0 = mt * 64;

    int rowg = row0 + mw * 32 + l31;
    const float* aptr = ((rowg < NR) ? latents + (size_t)rowg * D
                                     : boot + (size_t)(rowg - NR) * D) + lhi * 8;
    const char* bsrc = WpackB + (size_t)nh * 16384;   // tile t at + t*32768

    f32x16 acc0, acc1;
    #pragma unroll
    for (int r = 0; r < 16; ++r) { acc0[r] = 0.f; acc1[r] = 0.f; }

    float4 A0[8], A1[8], A2[8], A3[8];
    const int stoff = wave * 4096 + lane * 16;

#define STAGE(T, BUF) do {                                           \
        const char* s_ = bsrc + (size_t)(T) * 32768 + stoff;         \
        char* d_ = &ldsB[BUF][0] + stoff;                            \
        glds16(s_,        d_);                                       \
        glds16(s_ + 1024, d_ + 1024);                                \
        glds16(s_ + 2048, d_ + 2048);                                \
        glds16(s_ + 3072, d_ + 3072);                                \
    } while (0)

#define LOADA(SET, T) do {                                           \
        const float* a_ = aptr + (size_t)(T) * 64;                   \
        SET[0] = *(const float4*)(a_);      SET[1] = *(const float4*)(a_ + 4);  \
        SET[2] = *(const float4*)(a_ + 16); SET[3] = *(const float4*)(a_ + 20); \
        SET[4] = *(const float4*)(a_ + 32); SET[5] = *(const float4*)(a_ + 36); \
        SET[6] = *(const float4*)(a_ + 48); SET[7] = *(const float4*)(a_ + 52); \
    } while (0)

#define COMPUTE(BUF, SET) do {                                       \
        const char* base_ = &ldsB[BUF][0] + nw * 2048 + lhi * 512 + l31 * 16; \
        _Pragma("unroll")                                            \
        for (int ks = 0; ks < 4; ++ks) {                             \
            short8 b0_ = *(const short8*)(base_ + ks * 4096);        \
            short8 b1_ = *(const short8*)(base_ + ks * 4096 + 1024); \
            short8 a_  = mk8(pkbf(SET[2*ks].x, SET[2*ks].y),         \
                             pkbf(SET[2*ks].z, SET[2*ks].w),         \
                             pkbf(SET[2*ks+1].x, SET[2*ks+1].y),     \
                             pkbf(SET[2*ks+1].z, SET[2*ks+1].w));    \
            acc0 = __builtin_amdgcn_mfma_f32_32x32x16_bf16(a_, b0_, acc0, 0, 0, 0); \
            acc1 = __builtin_amdgcn_mfma_f32_32x32x16_bf16(a_, b1_, acc1, 0, 0, 0); \
        }                                                            \
    } while (0)

#define BAR()   __builtin_amdgcn_s_barrier()
#define SCHED() __builtin_amdgcn_sched_barrier(0)
#define WAITV36() asm volatile("s_waitcnt vmcnt(36)" ::: "memory")
#define WAITV24() asm volatile("s_waitcnt vmcnt(24)" ::: "memory")
#define WAITV12() asm volatile("s_waitcnt vmcnt(12)" ::: "memory")
#define WAITV0()  asm volatile("s_waitcnt vmcnt(0)"  ::: "memory")

    // prologue: prime 3 tiles
    STAGE(0, 0); LOADA(A0, 0);
    STAGE(1, 1); LOADA(A1, 1);
    STAGE(2, 2); LOADA(A2, 2);

    for (int t = 0; t + 7 < NT; t += 4) {
        BAR(); SCHED(); STAGE(t + 3, 3); LOADA(A3, t + 3);
        SCHED(); WAITV36(); BAR(); SCHED(); COMPUTE(0, A0);
        BAR(); SCHED(); STAGE(t + 4, 0); LOADA(A0, t + 4);
        SCHED(); WAITV36(); BAR(); SCHED(); COMPUTE(1, A1);
        BAR(); SCHED(); STAGE(t + 5, 1); LOADA(A1, t + 5);
        SCHED(); WAITV36(); BAR(); SCHED(); COMPUTE(2, A2);
        BAR(); SCHED(); STAGE(t + 6, 2); LOADA(A2, t + 6);
        SCHED(); WAITV36(); BAR(); SCHED(); COMPUTE(3, A3);
    }
    // tail: tiles NT-4..NT-1 in bufs 0..3 (A0..A3); stage NT-1 first, then drain
    BAR(); SCHED(); STAGE(NT - 1, 3); LOADA(A3, NT - 1);
    SCHED(); WAITV36(); BAR(); SCHED(); COMPUTE(0, A0);
    BAR(); SCHED(); WAITV24(); BAR(); SCHED(); COMPUTE(1, A1);
    BAR(); SCHED(); WAITV12(); BAR(); SCHED(); COMPUTE(2, A2);
    BAR(); SCHED(); WAITV0();  BAR(); SCHED(); COMPUTE(3, A3);

#undef STAGE
#undef LOADA
#undef COMPUTE
#undef BAR
#undef SCHED
#undef WAITV36
#undef WAITV24
#undef WAITV12
#undef WAITV0

    // epilogue: wave stores its 32x64 tile. C layout: col=lane&31, row=(r&3)+8*(r>>2)+4*lhi
    #pragma unroll
    for (int i = 0; i < 2; ++i) {
        int col = nh * 128 + nw * 64 + i * 32 + l31;
        if (col < NBINS) {
            float bias = bvec[col];
            const f32x16& a = i ? acc1 : acc0;
            #pragma unroll
            for (int r = 0; r < 16; ++r) {
                int row = row0 + mw * 32 + (r & 3) + 8 * (r >> 2) + 4 * lhi;
                logits[(size_t)row * NBINS + col] = a[r] + bias;
            }
        }
    }
}

// per-row softmax stats: value = softmax(l)@centers, logZ
__global__ __launch_bounds__(256) void softmax_stats(
    const float* __restrict__ logits, float* __restrict__ values,
    float* __restrict__ logZ, int R)
{
    int row  = blockIdx.x * 4 + (threadIdx.x >> 6);
    int lane = threadIdx.x & 63;
    if (row >= R) return;
    const float* lp = logits + (size_t)row * NBINS;
    const float step = (float)(40.0 / 254.0);

    float l[4];
    float m = -INFINITY;
    #pragma unroll
    for (int u = 0; u < 4; ++u) {
        int idx = lane + 64 * u;
        l[u] = (idx < NBINS) ? lp[idx] : -INFINITY;
        m = fmaxf(m, l[u]);
    }
    #pragma unroll
    for (int sh = 32; sh >= 1; sh >>= 1) m = fmaxf(m, __shfl_xor(m, sh, 64));

    float s = 0.f, sc = 0.f;
    #pragma unroll
    for (int u = 0; u < 4; ++u) {
        int idx = lane + 64 * u;
        if (idx < NBINS) {
            float e = __expf(l[u] - m);
            s  += e;
            sc += e * (BIN_LO_F + step * (float)idx);
        }
    }
    #pragma unroll
    for (int sh = 32; sh >= 1; sh >>= 1) {
        s  += __shfl_xor(s, sh, 64);
        sc += __shfl_xor(sc, sh, 64);
    }
    if (lane == 0) {
        values[row] = sc / s;
        logZ[row]   = m + __logf(s);
    }
}

__global__ void lambda_returns_k(
    const float* __restrict__ rewards, const float* __restrict__ dones,
    const float* __restrict__ values, float* __restrict__ returns,
    int B, int H, int NR)
{
    int b = blockIdx.x * blockDim.x + threadIdx.x;
    if (b >= B) return;
    const float gamma = 0.997f;
    const float lam   = 0.95f;
    const float oml   = (float)(1.0 - 0.95);
    float bootv = values[NR + b];
    float g = bootv;
    for (int h = H - 1; h >= 0; --h) {
        float nv   = (h == H - 1) ? bootv : values[b * H + h + 1];
        float mask = 1.0f - dones[b * H + h];
        g = rewards[b * H + h] + gamma * mask * (oml * nv + lam * g);
        returns[b * H + h] = g;
    }
}

__global__ __launch_bounds__(256) void loss_moments(
    const float* __restrict__ logits, const float* __restrict__ logZ,
    const float* __restrict__ values, const float* __restrict__ returns,
    double* __restrict__ accum, int NR)
{
    int row = blockIdx.x * blockDim.x + threadIdx.x;
    double lsum = 0, vsum = 0, v2 = 0, rsum = 0, r2 = 0;
    if (row < NR) {
        float v   = values[row];
        float ret = returns[row];
        float cl  = fminf(fmaxf(ret, BIN_LO_F), BIN_HI_F);
        const float step = (float)(40.0 / 254.0);
        float pos = (cl - BIN_LO_F) / step;
        int low = (int)floorf(pos);
        low = min(max(low, 0), NBINS - 2);
        float frac = pos - (float)low;
        const float* lp = logits + (size_t)row * NBINS;
        float llo = lp[low], lhi = lp[low + 1];
        float loss = logZ[row] - (1.f - frac) * llo - frac * lhi;
        lsum = (double)loss;
        vsum = (double)v;   v2 = (double)v * (double)v;
        rsum = (double)ret; r2 = (double)ret * (double)ret;
    }
    lsum = wave_reduce_sum_d(lsum);
    vsum = wave_reduce_sum_d(vsum);
    v2   = wave_reduce_sum_d(v2);
    rsum = wave_reduce_sum_d(rsum);
    r2   = wave_reduce_sum_d(r2);
    if ((threadIdx.x & 63) == 0) {
        atomicAdd(&accum[0], lsum);
        atomicAdd(&accum[1], vsum);
        atomicAdd(&accum[2], v2);
        atomicAdd(&accum[3], rsum);
        atomicAdd(&accum[4], r2);
    }
}

__global__ void finalize_k(const double* __restrict__ accum,
                           float* __restrict__ out, int NR)
{
    if (threadIdx.x == 0 && blockIdx.x == 0) {
        double n  = (double)NR;
        double vl = accum[0] / n;
        double mv = accum[1] / n;
        double vv = (accum[2] - n * mv * mv) / (n - 1.0);
        double mr = accum[3] / n;
        double vr = (accum[4] - n * mr * mr) / (n - 1.0);
        out[0] = (float)(0.5 * vl);
        out[1] = (float)vl;
        out[2] = (float)mv;
        out[3] = (float)mr;
        out[4] = (float)sqrt(vv > 0.0 ? vv : 0.0);
        out[5] = (float)sqrt(vr > 0.0 ? vr : 0.0);
    }
}

extern "C" void kernel_launch(void* const* d_in, const int* in_sizes, int n_in,
                              void* d_out, int out_size, void* d_ws, size_t ws_size,
                              hipStream_t stream) {
    const float* latents = (const float*)d_in[0];
    const float* rewards = (const float*)d_in[1];
    const float* dones   = (const float*)d_in[2];
    const float* boot    = (const float*)d_in[3];
    const float* W       = (const float*)d_in[4];
    const float* bvec    = (const float*)d_in[5];
    float* out = (float*)d_out;

    const int BH = in_sizes[1];          // B*H = 16384
    const int D  = in_sizes[0] / BH;     // 4096
    const int B  = in_sizes[3] / D;      // 1024
    const int H  = BH / B;               // 16
    const int NR = BH;
    const int R  = NR + B;               // 17408

    char* ws = (char*)d_ws;
    size_t off = 0;
    float* logits = (float*)(ws + off); off += (size_t)R * NBINS * sizeof(float);
    off = (off + 255) & ~(size_t)255;
    float* values = (float*)(ws + off); off += (size_t)R * sizeof(float);
    float* logZ   = (float*)(ws + off); off += (size_t)R * sizeof(float);
    float* rets   = (float*)(ws + off); off += (size_t)NR * sizeof(float);
    off = (off + 255) & ~(size_t)255;
    double* accum = (double*)(ws + off); off += 64;
    off = (off + 255) & ~(size_t)255;
    char* WpackB  = ws + off; off += (size_t)(D / 64) * 32768;   // 2 MB

    hipMemsetAsync(accum, 0, 64, stream);

    const int NT = D / 64;
    const int packUnits = NT * 2048;                 // 16B units
    pack_w3<<<packUnits / 256, 256, 0, stream>>>(W, WpackB);

    const int nwg = 2 * (R / 64);                    // 544
    gemm_mfma_v7<<<nwg, 256, 0, stream>>>(latents, boot, WpackB, bvec, logits,
                                          NR, R, D, nwg / 8);
    softmax_stats<<<(R + 3) / 4, 256, 0, stream>>>(logits, values, logZ, R);
    lambda_returns_k<<<(B + 255) / 256, 256, 0, stream>>>(rewards, dones, values, rets, B, H, NR);
    loss_moments<<<(NR + 255) / 256, 256, 0, stream>>>(logits, logZ, values, rets, accum, NR);
    finalize_k<<<1, 64, 0, stream>>>(accum, out, NR);
}

// Round 8
// 258.556 us; speedup vs baseline: 2.0586x; 1.0417x over previous
//
#include <hip/hip_runtime.h>
#include <math.h>

#define NBINS 255
#define BIN_LO_F (-20.0f)
#define BIN_HI_F (20.0f)

typedef __attribute__((ext_vector_type(8))) short short8;
typedef __attribute__((ext_vector_type(16))) float f32x16;

__device__ __forceinline__ unsigned short f2bf(float f) {
    unsigned u = __builtin_bit_cast(unsigned, f);
    unsigned r = u + 0x7fffu + ((u >> 16) & 1u);
    return (unsigned short)(r >> 16);
}

// packed RNE f32x2 -> bf16x2
__device__ __forceinline__ unsigned pkbf(float lo, float hi) {
    unsigned d;
    asm("v_cvt_pk_bf16_f32 %0, %1, %2" : "=v"(d) : "v"(lo), "v"(hi));
    return d;
}

__device__ __forceinline__ short8 mk8(unsigned a, unsigned b, unsigned c, unsigned d) {
    union { unsigned u[4]; short8 s; } t;
    t.u[0] = a; t.u[1] = b; t.u[2] = c; t.u[3] = d;
    return t.s;
}

__device__ __forceinline__ void glds16(const void* g, void* l) {
    __builtin_amdgcn_global_load_lds(
        (const __attribute__((address_space(1))) unsigned int*)g,
        (__attribute__((address_space(3))) unsigned int*)l, 16, 0, 0);
}

__device__ __forceinline__ double wave_reduce_sum_d(double v) {
    #pragma unroll
    for (int m = 32; m >= 1; m >>= 1) v += __shfl_xor(v, m, 64);
    return v;
}

// Pack W (D,255) fp32 -> bf16 image, one 16 KB block per K-step of 32:
// 16B unit u: kt=u>>10, v=u&1023: ks=v>>9, lhi=(v>>8)&1, gcol=(v>>5)&7, c31=v&31.
// content elem e: k = kt*32 + ks*16 + lhi*8 + e, col = gcol*32 + c31 (col 255 -> 0 pad).
// GEMM B-frag read (gcol, ks) is 2x512B contiguous per 64 lanes -> conflict-free.
__global__ __launch_bounds__(256) void pack_w4(
    const float* __restrict__ W, char* __restrict__ WpackB)
{
    int u = blockIdx.x * 256 + threadIdx.x;
    int kt = u >> 10;
    int v  = u & 1023;
    int ks = v >> 9;
    int lh = (v >> 8) & 1;
    int gcol = (v >> 5) & 7;
    int c31  = v & 31;
    int col  = gcol * 32 + c31;
    int k0   = kt * 32 + ks * 16 + lh * 8;
    short8 s;
    #pragma unroll
    for (int e = 0; e < 8; ++e)
        s[e] = (col < NBINS) ? (short)f2bf(W[(size_t)(k0 + e) * NBINS + col]) : (short)0;
    *(short8*)(WpackB + (size_t)u * 16) = s;
}

// v8: full-line-streaming GEMM. BM=32 x BN=256 (A read ONCE), BK=32, grid R/32=544,
// 256 thr = 4 waves = 4 col-groups of 64, wave tile 32x64, acc 2 x f32x16.
// A: global_load_lds row-major (1 instr = 8 rows x 128B = 16 full lines, each ONCE);
//    XOR-swizzled on BOTH sides (source chunk ^= row&7; ds_read applies same XOR);
//    fp32 in LDS, cvt_pk -> bf16 on read. B: 4 glds/wave from pre-packed linear image.
// Depth-3 counted vmcnt (batch=5 glds -> vmcnt(15)), 4 buffers (80 KB, 2 blocks/CU).
__global__ __launch_bounds__(256, 2) void gemm_mfma_v8(
    const float* __restrict__ latents, const float* __restrict__ boot,
    const char* __restrict__ WpackB, const float* __restrict__ bvec,
    float* __restrict__ logits, int NR, int R, int D, int nwg8)
{
    __shared__ __align__(16) char ldsA[4][4096];
    __shared__ __align__(16) char ldsB[4][16384];

    const int tid  = threadIdx.x;
    const int wave = tid >> 6, lane = tid & 63;
    const int l31  = lane & 31, lhi = lane >> 5;
    const int NT   = D >> 5;                 // 128 K-steps of 32 (NT % 4 == 0)

    // XCD-aware bijective swizzle (544 % 8 == 0)
    int bid  = blockIdx.x;
    int work = (bid & 7) * nwg8 + (bid >> 3);
    const int row0 = work * 32;

    // A staging: wave stages rows wave*8 .. +8; lane -> row wave*8+(lane>>3), phys chunk lane&7.
    // Source chunk = phys ^ (row&7)  (XOR pre-swizzle of the global source).
    const int arow_loc = (wave << 3) + (lane >> 3);          // 0..31
    const int arow = row0 + arow_loc;
    const float* arowp = (arow < NR) ? latents + (size_t)arow * D
                                     : boot + (size_t)(arow - NR) * D;
    const float* asrc = arowp + (((lane & 7) ^ (arow_loc & 7)) << 2);

    const int abase = l31 << 7;              // l31 * 128
    const int axor  = l31 & 7;

    f32x16 acc0, acc1;
    #pragma unroll
    for (int r = 0; r < 16; ++r) { acc0[r] = 0.f; acc1[r] = 0.f; }

#define STAGE(T, BUF) do {                                                  \
        glds16(asrc + (size_t)(T) * 32, &ldsA[BUF][(wave << 10) + (lane << 4)]); \
        const char* bs_ = WpackB + (size_t)(T) * 16384 + (wave << 12) + (lane << 4); \
        char* bd_ = &ldsB[BUF][(wave << 12) + (lane << 4)];                 \
        glds16(bs_,        bd_);                                            \
        glds16(bs_ + 1024, bd_ + 1024);                                     \
        glds16(bs_ + 2048, bd_ + 2048);                                     \
        glds16(bs_ + 3072, bd_ + 3072);                                     \
    } while (0)

#define COMPUTE(BUF) do {                                                   \
        const char* ab_ = &ldsA[BUF][0];                                    \
        const char* bb_ = &ldsB[BUF][0] + (wave << 10) + (l31 << 4);        \
        _Pragma("unroll")                                                   \
        for (int ks = 0; ks < 2; ++ks) {                                    \
            int c0_ = ks * 4 + lhi * 2;                                     \
            float4 f0_ = *(const float4*)(ab_ + abase + (((c0_ + 0) ^ axor) << 4)); \
            float4 f1_ = *(const float4*)(ab_ + abase + (((c0_ + 1) ^ axor) << 4)); \
            short8 a_  = mk8(pkbf(f0_.x, f0_.y), pkbf(f0_.z, f0_.w),        \
                             pkbf(f1_.x, f1_.y), pkbf(f1_.z, f1_.w));       \
            short8 b0_ = *(const short8*)(bb_ + ((ks * 2 + lhi) << 12));    \
            short8 b1_ = *(const short8*)(bb_ + ((ks * 2 + lhi) << 12) + 512); \
            acc0 = __builtin_amdgcn_mfma_f32_32x32x16_bf16(a_, b0_, acc0, 0, 0, 0); \
            acc1 = __builtin_amdgcn_mfma_f32_32x32x16_bf16(a_, b1_, acc1, 0, 0, 0); \
        }                                                                   \
    } while (0)

#define BAR()   __builtin_amdgcn_s_barrier()
#define SCHED() __builtin_amdgcn_sched_barrier(0)
#define WAITV15() asm volatile("s_waitcnt vmcnt(15)" ::: "memory")
#define WAITV10() asm volatile("s_waitcnt vmcnt(10)" ::: "memory")
#define WAITV5()  asm volatile("s_waitcnt vmcnt(5)"  ::: "memory")
#define WAITV0()  asm volatile("s_waitcnt vmcnt(0)"  ::: "memory")

    // prologue: prime 3 K-steps (15 loads in flight)
    STAGE(0, 0); STAGE(1, 1); STAGE(2, 2);

    int t = 0;
    for (; t + 7 < NT; t += 4) {
        BAR(); SCHED(); STAGE(t + 3, 3); SCHED(); WAITV15(); BAR(); SCHED(); COMPUTE(0);
        BAR(); SCHED(); STAGE(t + 4, 0); SCHED(); WAITV15(); BAR(); SCHED(); COMPUTE(1);
        BAR(); SCHED(); STAGE(t + 5, 1); SCHED(); WAITV15(); BAR(); SCHED(); COMPUTE(2);
        BAR(); SCHED(); STAGE(t + 6, 2); SCHED(); WAITV15(); BAR(); SCHED(); COMPUTE(3);
    }
    // tail: 4 phases (NT % 4 == 0), drain 15 -> 0
    BAR(); SCHED(); STAGE(t + 3, 3); SCHED(); WAITV15(); BAR(); SCHED(); COMPUTE(0);
    BAR(); SCHED(); WAITV10(); BAR(); SCHED(); COMPUTE(1);
    BAR(); SCHED(); WAITV5();  BAR(); SCHED(); COMPUTE(2);
    BAR(); SCHED(); WAITV0();  BAR(); SCHED(); COMPUTE(3);

#undef STAGE
#undef COMPUTE
#undef BAR
#undef SCHED
#undef WAITV15
#undef WAITV10
#undef WAITV5
#undef WAITV0

    // epilogue: wave's 32x64 tile. C layout: col=lane&31, row=(r&3)+8*(r>>2)+4*lhi
    #pragma unroll
    for (int i = 0; i < 2; ++i) {
        int col = wave * 64 + i * 32 + l31;
        if (col < NBINS) {
            float bias = bvec[col];
            const f32x16& a = i ? acc1 : acc0;
            #pragma unroll
            for (int r = 0; r < 16; ++r) {
                int row = row0 + (r & 3) + 8 * (r >> 2) + 4 * lhi;
                logits[(size_t)row * NBINS + col] = a[r] + bias;
            }
        }
    }
}

// per-row softmax stats: value = softmax(l)@centers, logZ
__global__ __launch_bounds__(256) void softmax_stats(
    const float* __restrict__ logits, float* __restrict__ values,
    float* __restrict__ logZ, int R)
{
    int row  = blockIdx.x * 4 + (threadIdx.x >> 6);
    int lane = threadIdx.x & 63;
    if (row >= R) return;
    const float* lp = logits + (size_t)row * NBINS;
    const float step = (float)(40.0 / 254.0);

    float l[4];
    float m = -INFINITY;
    #pragma unroll
    for (int u = 0; u < 4; ++u) {
        int idx = lane + 64 * u;
        l[u] = (idx < NBINS) ? lp[idx] : -INFINITY;
        m = fmaxf(m, l[u]);
    }
    #pragma unroll
    for (int sh = 32; sh >= 1; sh >>= 1) m = fmaxf(m, __shfl_xor(m, sh, 64));

    float s = 0.f, sc = 0.f;
    #pragma unroll
    for (int u = 0; u < 4; ++u) {
        int idx = lane + 64 * u;
        if (idx < NBINS) {
            float e = __expf(l[u] - m);
            s  += e;
            sc += e * (BIN_LO_F + step * (float)idx);
        }
    }
    #pragma unroll
    for (int sh = 32; sh >= 1; sh >>= 1) {
        s  += __shfl_xor(s, sh, 64);
        sc += __shfl_xor(sc, sh, 64);
    }
    if (lane == 0) {
        values[row] = sc / s;
        logZ[row]   = m + __logf(s);
    }
}

__global__ void lambda_returns_k(
    const float* __restrict__ rewards, const float* __restrict__ dones,
    const float* __restrict__ values, float* __restrict__ returns,
    int B, int H, int NR)
{
    int b = blockIdx.x * blockDim.x + threadIdx.x;
    if (b >= B) return;
    const float gamma = 0.997f;
    const float lam   = 0.95f;
    const float oml   = (float)(1.0 - 0.95);
    float bootv = values[NR + b];
    float g = bootv;
    for (int h = H - 1; h >= 0; --h) {
        float nv   = (h == H - 1) ? bootv : values[b * H + h + 1];
        float mask = 1.0f - dones[b * H + h];
        g = rewards[b * H + h] + gamma * mask * (oml * nv + lam * g);
        returns[b * H + h] = g;
    }
}

__global__ __launch_bounds__(256) void loss_moments(
    const float* __restrict__ logits, const float* __restrict__ logZ,
    const float* __restrict__ values, const float* __restrict__ returns,
    double* __restrict__ accum, int NR)
{
    int row = blockIdx.x * blockDim.x + threadIdx.x;
    double lsum = 0, vsum = 0, v2 = 0, rsum = 0, r2 = 0;
    if (row < NR) {
        float v   = values[row];
        float ret = returns[row];
        float cl  = fminf(fmaxf(ret, BIN_LO_F), BIN_HI_F);
        const float step = (float)(40.0 / 254.0);
        float pos = (cl - BIN_LO_F) / step;
        int low = (int)floorf(pos);
        low = min(max(low, 0), NBINS - 2);
        float frac = pos - (float)low;
        const float* lp = logits + (size_t)row * NBINS;
        float llo = lp[low], lhi = lp[low + 1];
        float loss = logZ[row] - (1.f - frac) * llo - frac * lhi;
        lsum = (double)loss;
        vsum = (double)v;   v2 = (double)v * (double)v;
        rsum = (double)ret; r2 = (double)ret * (double)ret;
    }
    lsum = wave_reduce_sum_d(lsum);
    vsum = wave_reduce_sum_d(vsum);
    v2   = wave_reduce_sum_d(v2);
    rsum = wave_reduce_sum_d(rsum);
    r2   = wave_reduce_sum_d(r2);
    if ((threadIdx.x & 63) == 0) {
        atomicAdd(&accum[0], lsum);
        atomicAdd(&accum[1], vsum);
        atomicAdd(&accum[2], v2);
        atomicAdd(&accum[3], rsum);
        atomicAdd(&accum[4], r2);
    }
}

__global__ void finalize_k(const double* __restrict__ accum,
                           float* __restrict__ out, int NR)
{
    if (threadIdx.x == 0 && blockIdx.x == 0) {
        double n  = (double)NR;
        double vl = accum[0] / n;
        double mv = accum[1] / n;
        double vv = (accum[2] - n * mv * mv) / (n - 1.0);
        double mr = accum[3] / n;
        double vr = (accum[4] - n * mr * mr) / (n - 1.0);
        out[0] = (float)(0.5 * vl);
        out[1] = (float)vl;
        out[2] = (float)mv;
        out[3] = (float)mr;
        out[4] = (float)sqrt(vv > 0.0 ? vv : 0.0);
        out[5] = (float)sqrt(vr > 0.0 ? vr : 0.0);
    }
}

extern "C" void kernel_launch(void* const* d_in, const int* in_sizes, int n_in,
                              void* d_out, int out_size, void* d_ws, size_t ws_size,
                              hipStream_t stream) {
    const float* latents = (const float*)d_in[0];
    const float* rewards = (const float*)d_in[1];
    const float* dones   = (const float*)d_in[2];
    const float* boot    = (const float*)d_in[3];
    const float* W       = (const float*)d_in[4];
    const float* bvec    = (const float*)d_in[5];
    float* out = (float*)d_out;

    const int BH = in_sizes[1];          // B*H = 16384
    const int D  = in_sizes[0] / BH;     // 4096
    const int B  = in_sizes[3] / D;      // 1024
    const int H  = BH / B;               // 16
    const int NR = BH;
    const int R  = NR + B;               // 17408

    char* ws = (char*)d_ws;
    size_t off = 0;
    float* logits = (float*)(ws + off); off += (size_t)R * NBINS * sizeof(float);
    off = (off + 255) & ~(size_t)255;
    float* values = (float*)(ws + off); off += (size_t)R * sizeof(float);
    float* logZ   = (float*)(ws + off); off += (size_t)R * sizeof(float);
    float* rets   = (float*)(ws + off); off += (size_t)NR * sizeof(float);
    off = (off + 255) & ~(size_t)255;
    double* accum = (double*)(ws + off); off += 64;
    off = (off + 255) & ~(size_t)255;
    char* WpackB  = ws + off; off += (size_t)(D / 32) * 16384;   // 2 MB

    hipMemsetAsync(accum, 0, 64, stream);

    const int NT = D / 32;
    const int packUnits = NT * 1024;                 // 16B units
    pack_w4<<<packUnits / 256, 256, 0, stream>>>(W, WpackB);

    const int nwg = R / 32;                          // 544
    gemm_mfma_v8<<<nwg, 256, 0, stream>>>(latents, boot, WpackB, bvec, logits,
                                          NR, R, D, nwg / 8);
    softmax_stats<<<(R + 3) / 4, 256, 0, stream>>>(logits, values, logZ, R);
    lambda_returns_k<<<(B + 255) / 256, 256, 0, stream>>>(rewards, dones, values, rets, B, H, NR);
    loss_moments<<<(NR + 255) / 256, 256, 0, stream>>>(logits, logZ, values, rets, accum, NR);
    finalize_k<<<1, 64, 0, stream>>>(accum, out, NR);
}